// Round 5
// baseline (162.348 us; speedup 1.0000x reference)
//
#include <hip/hip_runtime.h>
#include <hip/hip_bf16.h>
#include <math.h>

#define LN_EPS 1e-5f

typedef unsigned short ushortT;
typedef short bf16x8 __attribute__((ext_vector_type(8)));
typedef float f32x4 __attribute__((ext_vector_type(4)));

// ws layout (float offsets)
#define WS_QP   0            // q_p * scale (128)
#define WS_V0   128          // v0 (128)
#define WS_S0   256          // s0 scalar
#define WS_LL   258          // softmax denominator L
#define WS_E0   259          // exp(s0 - M)
#define WS_H1P  512          // 16*256 h1 partials
#define WS_PART 4608         // per-block partials: [acc 128][m][l][pad] stride 132
#define PART_STRIDE 132
#define PART_M 128
#define PART_L 129
#define WS_WTS  108000       // per-block softmax weights (NB floats)
#define WS_GP   109000       // 32 x 128 combiner partial sums
#define NCOMB   32
#define WS_WPT  131072       // ushort region: WpT[256][1024] bf16 (512KB)
#define WS_WKVT 262144       // ushort region: WkvT[256][256] bf16 (128KB)

__device__ __forceinline__ float elu1(float x){ return x > 0.f ? x : expm1f(x); }
__device__ __forceinline__ unsigned short f2bf(float x){
  unsigned u = __float_as_uint(x);
  return (unsigned short)((u + 0x7fffu + ((u >> 16) & 1u)) >> 16);
}
__device__ __forceinline__ unsigned pk2(float lo, float hi){
  union { __hip_bfloat162 h; unsigned u; } cv;
  cv.h = __float22bfloat162_rn(make_float2(lo, hi));
  return cv.u;
}
// async global->LDS DMA, 16B/lane, linear dest (wave-uniform base + lane*16)
__device__ __forceinline__ void dma16(const void* g, void* l) {
  __builtin_amdgcn_global_load_lds(
      (const __attribute__((address_space(1))) unsigned int*)g,
      (__attribute__((address_space(3))) unsigned int*)l, 16, 0, 0);
}
template<int N> __device__ __forceinline__ void vwait() {
  asm volatile("s_waitcnt vmcnt(%0)" :: "i"(N) : "memory");
}
__device__ __forceinline__ void lwait0() {
  asm volatile("s_waitcnt lgkmcnt(0)" ::: "memory");
}
__device__ __forceinline__ void sbar()   { __builtin_amdgcn_s_barrier(); }
__device__ __forceinline__ void schedb() { __builtin_amdgcn_sched_barrier(0); }

// ---------------- K_prep: transpose+convert Wp and Wqkv(k|v) to bf16 ----------------
__global__ __launch_bounds__(256) void k_prep(const float* __restrict__ Wp,
    const float* __restrict__ Wqkv, ushortT* __restrict__ wpt, ushortT* __restrict__ wkvt)
{
  int bb = blockIdx.x, t = threadIdx.x;
  if (bb < 256) {
    int k0 = bb * 4;
    unsigned lo, hi;
    lo = (unsigned)f2bf(Wp[(size_t)(k0 + 0) * 256 + t]) |
         ((unsigned)f2bf(Wp[(size_t)(k0 + 1) * 256 + t]) << 16);
    hi = (unsigned)f2bf(Wp[(size_t)(k0 + 2) * 256 + t]) |
         ((unsigned)f2bf(Wp[(size_t)(k0 + 3) * 256 + t]) << 16);
    *(uint2*)&wpt[t * 1024 + k0] = make_uint2(lo, hi);
  } else {
    int k0 = (bb - 256) * 4;
    unsigned lo, hi;
    lo = (unsigned)f2bf(Wqkv[(size_t)(k0 + 0) * 384 + 128 + t]) |
         ((unsigned)f2bf(Wqkv[(size_t)(k0 + 1) * 384 + 128 + t]) << 16);
    hi = (unsigned)f2bf(Wqkv[(size_t)(k0 + 2) * 384 + 128 + t]) |
         ((unsigned)f2bf(Wqkv[(size_t)(k0 + 3) * 384 + 128 + t]) << 16);
    *(uint2*)&wkvt[t * 256 + k0] = make_uint2(lo, hi);
  }
}

// ---------------- K0: h1 partial dots ----------------
__global__ __launch_bounds__(256) void k_h1(const float* __restrict__ x,
    const float* __restrict__ W1, int d_omic, float* __restrict__ ws)
{
  int g = blockIdx.x, tid = threadIdx.x;
  int i0 = g * 99, i1 = min(i0 + 99, d_omic);
  __shared__ float xs[112];
  for (int i = i0 + tid; i < i1; i += 256) xs[i - i0] = x[i];
  __syncthreads();
  float s = 0.f;
  for (int i = i0; i < i1; i++) s = fmaf(xs[i - i0], W1[(size_t)i * 256 + tid], s);
  ws[WS_H1P + g * 256 + tid] = s;
}

// ---------------- K1: omic MLP + token0 LN1 + q_p/k_p/v0 + s0 (exact fp32) ----------------
__global__ __launch_bounds__(256) void k_omic(
    const float* __restrict__ b1,
    const float* __restrict__ W2, const float* __restrict__ b2,
    const float* __restrict__ Wqkv,
    const float* __restrict__ ln1_g, const float* __restrict__ ln1_b,
    float* __restrict__ ws)
{
  __shared__ float h1[256];
  __shared__ float xn0[256];
  __shared__ float qs[128], ks[128];
  __shared__ float red[8];
  int tid = threadIdx.x, lane = tid & 63, wave = tid >> 6;

  float s = b1[tid];
  for (int g = 0; g < 16; g++) s += ws[WS_H1P + g * 256 + tid];
  h1[tid] = elu1(s);
  __syncthreads();

  s = b2[tid];
  for (int i = 0; i < 256; i++) s = fmaf(h1[i], W2[i * 256 + tid], s);
  float t0 = elu1(s);

  float ps = t0, pq = t0 * t0;
  for (int m = 1; m < 64; m <<= 1) { ps += __shfl_xor(ps, m); pq += __shfl_xor(pq, m); }
  if (lane == 0) { red[wave] = ps; red[4 + wave] = pq; }
  __syncthreads();
  float mu = (red[0] + red[1] + red[2] + red[3]) * (1.f / 256.f);
  float var = (red[4] + red[5] + red[6] + red[7]) * (1.f / 256.f) - mu * mu;
  float xn = (t0 - mu) * rsqrtf(var + LN_EPS) * ln1_g[tid] + ln1_b[tid];
  xn0[tid] = xn;
  __syncthreads();

  float a = 0.f;
  for (int j = 0; j < 256; j++) a = fmaf(xn0[j], Wqkv[j * 384 + tid], a);
  if (tid < 128) { float q = a * 0.088388347648318447f; qs[tid] = q; ws[WS_QP + tid] = q; }
  else           { ks[tid - 128] = a; }
  if (tid < 128) {
    float av = 0.f;
    for (int j = 0; j < 256; j++) av = fmaf(xn0[j], Wqkv[j * 384 + 256 + tid], av);
    ws[WS_V0 + tid] = av;
  }
  __syncthreads();
  float p = (tid < 128) ? qs[tid] * ks[tid] : 0.f;
  for (int m = 1; m < 64; m <<= 1) p += __shfl_xor(p, m);
  if (lane == 0) red[wave] = p;
  __syncthreads();
  if (tid == 0) ws[WS_S0] = red[0] + red[1] + red[2] + red[3];
}

// ---------------- K2: pipelined MFMA fused wsi@Wp -> LN1 -> [k|v] -> scores -> partials ----
// 3-deep counted-vmcnt pipeline (T3+T4): never drain vmcnt to 0 in the k-loop.
// D1[m=Wp-outcol][n=wsi-row] = WpT(A) x wsiT(B); C/D lane layout m89-verified.
__global__ __launch_bounds__(256, 2) void k_main(
    const float* __restrict__ wsi, int N,
    const ushortT* __restrict__ wpt, const ushortT* __restrict__ wkvt,
    const float* __restrict__ bp,
    const float* __restrict__ ln1_g, const float* __restrict__ ln1_b,
    float* __restrict__ ws)
{
  // SW: 3 x 16KB wpt slices  (phase2: [0..32K)=Xn, [32K..48K)=wkv slot A)
  // SS: 3 x 8KB  wsi slices  (phase2: [0..16K)=wkv slot B, [16K..24K)=red)
  __shared__ __align__(16) char SW[3 * 16384];
  __shared__ __align__(16) char SS[3 * 8192];
  __shared__ float wtsL[64];

  const int tid = threadIdx.x;
  const int lane = tid & 63, wv = tid >> 6;
  const int l15 = lane & 15, lh = lane >> 4;
  const int b = blockIdx.x, r0 = b * 64;

  // ---- per-lane DMA source offsets (inverse-swizzled; dest is linear) ----
  // wsi slice [64 rows][32 fp32]: 8 x 16B chunks/row; stored chunk c holds global chunk c^(row&7)
  int wsrc[2];
  #pragma unroll
  for (int i = 0; i < 2; ++i) {
    int row = 16 * wv + 8 * i + (lane >> 3);
    int c   = lane & 7;
    int gr  = r0 + row; gr = (gr < N) ? gr : (N - 1);   // clamp (pad rows masked later)
    wsrc[i] = gr * 1024 + ((c ^ (row & 7)) << 2);
  }
  // wpt/wkv slice [256 m][32 bf16]: pair-row layout: byte(m,c) = (m>>1)*128 + ((4*(m&1)+c)^((m>>1)&7))*16
  int psrc[4], kvsrc[4];
  #pragma unroll
  for (int j = 0; j < 4; ++j) {
    int p  = lane >> 3;
    int cc = (lane & 7) ^ (p & 7);
    int mj = 16 * j + 2 * p + (cc >> 2);        // local m in wave's 64 rows
    int m  = 64 * wv + mj;
    int c  = cc & 3;
    psrc[j]  = m * 1024 + c * 8;
    kvsrc[j] = m * 256  + c * 8;
  }
  // read-side constant offsets
  const unsigned afc = (unsigned)(((4 * (l15 & 1) + lh) ^ (l15 >> 1)) << 4);
  const unsigned bc0 = (unsigned)(((2 * lh)     ^ (l15 & 7)) << 4);
  const unsigned bc1 = (unsigned)(((2 * lh + 1) ^ (l15 & 7)) << 4);

  const f32x4 z4 = {0.f, 0.f, 0.f, 0.f};
  f32x4 acc[4][4];
  #pragma unroll
  for (int mt = 0; mt < 4; ++mt)
    #pragma unroll
    for (int nt = 0; nt < 4; ++nt) acc[mt][nt] = z4;

  auto stageP1 = [&](int kc, int slot) {
    char* ds = SS + slot * 8192 + wv * 2048;
    #pragma unroll
    for (int i = 0; i < 2; ++i) dma16(wsi + wsrc[i] + kc * 32, ds + i * 1024);
    char* dw = SW + slot * 16384 + wv * 4096;
    #pragma unroll
    for (int j = 0; j < 4; ++j) dma16(wpt + psrc[j] + kc * 32, dw + j * 1024);
  };
  auto computeP1 = [&](int slot) {
    const char* Wb = SW + slot * 16384 + wv * 4096;
    const char* Sb = SS + slot * 8192;
    bf16x8 af[4], bfr[4];
    #pragma unroll
    for (int mt = 0; mt < 4; ++mt)
      af[mt] = *(const bf16x8*)(Wb + (8 * mt + (l15 >> 1)) * 128 + afc);
    #pragma unroll
    for (int nt = 0; nt < 4; ++nt) {
      const char* p = Sb + (l15 + 16 * nt) * 128;
      uint4 ua = *(const uint4*)(p + bc0);
      uint4 ub = *(const uint4*)(p + bc1);
      union { unsigned u[4]; bf16x8 v; } cv;
      cv.u[0] = pk2(__uint_as_float(ua.x), __uint_as_float(ua.y));
      cv.u[1] = pk2(__uint_as_float(ua.z), __uint_as_float(ua.w));
      cv.u[2] = pk2(__uint_as_float(ub.x), __uint_as_float(ub.y));
      cv.u[3] = pk2(__uint_as_float(ub.z), __uint_as_float(ub.w));
      bfr[nt] = cv.v;
    }
    #pragma unroll
    for (int mt = 0; mt < 4; ++mt)
      #pragma unroll
      for (int nt = 0; nt < 4; ++nt)
        acc[mt][nt] = __builtin_amdgcn_mfma_f32_16x16x32_bf16(af[mt], bfr[nt], acc[mt][nt], 0, 0, 0);
  };

  // ---- phase 1 pipeline: 32 k32-slices, 3-deep, 6 DMA/wave/stage ----
  stageP1(0, 0); stageP1(1, 1); stageP1(2, 2);   // 18 ops in flight
  int slot = 0;
  for (int kc = 0; kc < 32; ++kc) {
    if (kc < 30) vwait<12>(); else if (kc == 30) vwait<6>(); else vwait<0>();
    sbar(); schedb();                 // stage(kc) landed for all waves
    computeP1(slot);
    sbar(); schedb();                 // all waves done reading slot
    if (kc < 29) stageP1(kc + 3, slot);
    slot = (slot == 2) ? 0 : slot + 1;
  }

  // ---- phase-2 prefetch issued under the LN phase (slots free after kc=31 barrier) ----
  auto stageKV = [&](int t) {
    char* dst = ((t & 1) ? SS : SW + 32768) + wv * 4096;
    #pragma unroll
    for (int j = 0; j < 4; ++j) dma16(wkvt + kvsrc[j] + t * 32, dst + j * 1024);
  };
  stageKV(0); stageKV(1);             // 8 ops in flight

  // ---- bias + LN1 ----
  float* red = (float*)(SS + 16384);
  float4 bp4[4], g4[4], b4[4];
  #pragma unroll
  for (int mt = 0; mt < 4; ++mt) {
    int m0 = 64 * wv + 16 * mt + 4 * lh;
    bp4[mt] = *(const float4*)&bp[m0];
    g4[mt]  = *(const float4*)&ln1_g[m0];
    b4[mt]  = *(const float4*)&ln1_b[m0];
  }
  float ps[4], pq[4];
  #pragma unroll
  for (int nt = 0; nt < 4; ++nt) { ps[nt] = 0.f; pq[nt] = 0.f; }
  #pragma unroll
  for (int mt = 0; mt < 4; ++mt) {
    const float bb4[4] = {bp4[mt].x, bp4[mt].y, bp4[mt].z, bp4[mt].w};
    #pragma unroll
    for (int nt = 0; nt < 4; ++nt)
      #pragma unroll
      for (int r = 0; r < 4; ++r) {
        float v = acc[mt][nt][r] + bb4[r];
        acc[mt][nt][r] = v;
        ps[nt] += v; pq[nt] += v * v;
      }
  }
  #pragma unroll
  for (int nt = 0; nt < 4; ++nt) {
    ps[nt] += __shfl_xor(ps[nt], 16); pq[nt] += __shfl_xor(pq[nt], 16);
    ps[nt] += __shfl_xor(ps[nt], 32); pq[nt] += __shfl_xor(pq[nt], 32);
  }
  if (lh == 0) {
    #pragma unroll
    for (int nt = 0; nt < 4; ++nt) {
      int row = l15 + 16 * nt;
      red[(wv * 64 + row) * 2]     = ps[nt];
      red[(wv * 64 + row) * 2 + 1] = pq[nt];
    }
  }
  lwait0(); sbar(); schedb();
  float mu[4], rstd[4];
  #pragma unroll
  for (int nt = 0; nt < 4; ++nt) {
    int row = l15 + 16 * nt;
    float s_ = 0.f, q_ = 0.f;
    #pragma unroll
    for (int w2 = 0; w2 < 4; ++w2) { s_ += red[(w2 * 64 + row) * 2]; q_ += red[(w2 * 64 + row) * 2 + 1]; }
    float m_ = s_ * (1.f / 256.f);
    float v_ = q_ * (1.f / 256.f) - m_ * m_;
    mu[nt] = m_; rstd[nt] = rsqrtf(v_ + LN_EPS);
  }
  // write xn (bf16, swizzled [row][col]) into SW[0..32K)
  #pragma unroll
  for (int nt = 0; nt < 4; ++nt) {
    int row = l15 + 16 * nt;
    unsigned rswz = (unsigned)((row & 7) << 4);
    #pragma unroll
    for (int mt = 0; mt < 4; ++mt) {
      float x0 = (acc[mt][nt][0] - mu[nt]) * rstd[nt] * g4[mt].x + b4[mt].x;
      float x1 = (acc[mt][nt][1] - mu[nt]) * rstd[nt] * g4[mt].y + b4[mt].y;
      float x2 = (acc[mt][nt][2] - mu[nt]) * rstd[nt] * g4[mt].z + b4[mt].z;
      float x3 = (acc[mt][nt][3] - mu[nt]) * rstd[nt] * g4[mt].w + b4[mt].w;
      unsigned p0 = pk2(x0, x1);
      unsigned p1 = pk2(x2, x3);
      int m0 = 64 * wv + 16 * mt + 4 * lh;
      unsigned off = (unsigned)(row * 512 + m0 * 2) ^ rswz;
      *(uint2*)(SW + off) = make_uint2(p0, p1);
    }
  }
  lwait0(); sbar(); schedb();          // Xn visible to all waves

  // ---- phase 2 pipeline: D2[m=kv-col][n=row] = WkvT(A) x xnT(B), 8 k32-slices, 2-deep ----
  f32x4 acc2[4][4];
  #pragma unroll
  for (int mt = 0; mt < 4; ++mt)
    #pragma unroll
    for (int nt = 0; nt < 4; ++nt) acc2[mt][nt] = z4;

  for (int kk = 0; kk < 8; ++kk) {
    if (kk < 7) vwait<4>(); else vwait<0>();
    sbar(); schedb();
    {
      const char* Pb = ((kk & 1) ? SS : SW + 32768) + wv * 4096;
      bf16x8 af[4], bfr[4];
      #pragma unroll
      for (int mt = 0; mt < 4; ++mt)
        af[mt] = *(const bf16x8*)(Pb + (8 * mt + (l15 >> 1)) * 128 + afc);
      #pragma unroll
      for (int nt = 0; nt < 4; ++nt) {
        int row = l15 + 16 * nt;
        unsigned off = (unsigned)(row * 512 + lh * 16 + kk * 64) ^ (unsigned)((row & 7) << 4);
        bfr[nt] = *(const bf16x8*)(SW + off);
      }
      #pragma unroll
      for (int mt = 0; mt < 4; ++mt)
        #pragma unroll
        for (int nt = 0; nt < 4; ++nt)
          acc2[mt][nt] = __builtin_amdgcn_mfma_f32_16x16x32_bf16(af[mt], bfr[nt], acc2[mt][nt], 0, 0, 0);
    }
    sbar(); schedb();
    if (kk < 6) stageKV(kk + 2);
  }

  float* part = ws + WS_PART + (size_t)b * PART_STRIDE;

  // ---- scores (waves 0,1 hold k-proj) ----
  if (wv < 2) {
    float4 qp4[4];
    #pragma unroll
    for (int mt = 0; mt < 4; ++mt)
      qp4[mt] = *(const float4*)&ws[WS_QP + 64 * wv + 16 * mt + 4 * lh];
    float sp[4];
    #pragma unroll
    for (int nt = 0; nt < 4; ++nt) {
      float s_ = 0.f;
      #pragma unroll
      for (int mt = 0; mt < 4; ++mt) {
        s_ = fmaf(qp4[mt].x, acc2[mt][nt][0], s_);
        s_ = fmaf(qp4[mt].y, acc2[mt][nt][1], s_);
        s_ = fmaf(qp4[mt].z, acc2[mt][nt][2], s_);
        s_ = fmaf(qp4[mt].w, acc2[mt][nt][3], s_);
      }
      sp[nt] = s_;
    }
    #pragma unroll
    for (int nt = 0; nt < 4; ++nt) {
      sp[nt] += __shfl_xor(sp[nt], 16);
      sp[nt] += __shfl_xor(sp[nt], 32);
    }
    if (lh == 0) {
      #pragma unroll
      for (int nt = 0; nt < 4; ++nt) red[wv * 64 + 16 * nt + l15] = sp[nt];
    }
  }
  __syncthreads();
  if (tid < 64) {
    int gr = r0 + tid;
    float s_ = red[tid] + red[64 + tid];
    if (gr >= N) s_ = -INFINITY;
    float mb = s_;
    #pragma unroll
    for (int m = 1; m < 64; m <<= 1) mb = fmaxf(mb, __shfl_xor(mb, m));
    float e = (gr < N) ? expf(s_ - mb) : 0.f;
    float l_ = e;
    #pragma unroll
    for (int m = 1; m < 64; m <<= 1) l_ += __shfl_xor(l_, m);
    wtsL[tid] = e;
    if (tid == 0) { part[PART_M] = mb; part[PART_L] = l_; }
  }
  __syncthreads();
  // ---- weighted-V partials (waves 2,3 hold v-proj) ----
  if (wv >= 2) {
    int wv2 = wv - 2;
    float wr[4];
    #pragma unroll
    for (int nt = 0; nt < 4; ++nt) wr[nt] = wtsL[16 * nt + l15];
    #pragma unroll
    for (int mt = 0; mt < 4; ++mt) {
      float vs0 = 0.f, vs1 = 0.f, vs2 = 0.f, vs3 = 0.f;
      #pragma unroll
      for (int nt = 0; nt < 4; ++nt) {
        vs0 = fmaf(wr[nt], acc2[mt][nt][0], vs0);
        vs1 = fmaf(wr[nt], acc2[mt][nt][1], vs1);
        vs2 = fmaf(wr[nt], acc2[mt][nt][2], vs2);
        vs3 = fmaf(wr[nt], acc2[mt][nt][3], vs3);
      }
      #pragma unroll
      for (int m = 1; m < 16; m <<= 1) {
        vs0 += __shfl_xor(vs0, m); vs1 += __shfl_xor(vs1, m);
        vs2 += __shfl_xor(vs2, m); vs3 += __shfl_xor(vs3, m);
      }
      if (l15 == 0)
        *(float4*)&part[64 * wv2 + 16 * mt + 4 * lh] = make_float4(vs0, vs1, vs2, vs3);
    }
  }
}

// ---------------- K_fin0: global max M, per-block weights, denominator L ----------------
__global__ __launch_bounds__(256) void k_fin0(float* __restrict__ ws, int NB)
{
  __shared__ float red[8];
  int tid = threadIdx.x, lane = tid & 63, wave = tid >> 6;
  const float* part = ws + WS_PART;
  float s0 = ws[WS_S0];

  float mloc = s0;
  for (int bb = tid; bb < NB; bb += 256) mloc = fmaxf(mloc, part[(size_t)bb * PART_STRIDE + PART_M]);
  for (int m = 1; m < 64; m <<= 1) mloc = fmaxf(mloc, __shfl_xor(mloc, m));
  if (lane == 0) red[wave] = mloc;
  __syncthreads();
  float M = fmaxf(fmaxf(red[0], red[1]), fmaxf(red[2], red[3]));

  float lp = 0.f;
  for (int bb = tid; bb < NB; bb += 256) {
    float w = expf(part[(size_t)bb * PART_STRIDE + PART_M] - M);
    ws[WS_WTS + bb] = w;
    lp = fmaf(part[(size_t)bb * PART_STRIDE + PART_L], w, lp);
  }
  for (int m = 1; m < 64; m <<= 1) lp += __shfl_xor(lp, m);
  __syncthreads();
  if (lane == 0) red[wave] = lp;
  __syncthreads();
  if (tid == 0) {
    float e0 = expf(s0 - M);
    ws[WS_LL] = red[0] + red[1] + red[2] + red[3] + e0;
    ws[WS_E0] = e0;
  }
}

// ---------------- K_fin1: 32-way parallel weighted partial combine ----------------
__global__ __launch_bounds__(128) void k_fin1(float* __restrict__ ws, int NB, int chunk)
{
  int g = blockIdx.x, col = threadIdx.x;
  int c0 = g * chunk, c1 = min(c0 + chunk, NB);
  const float* part = ws + WS_PART;
  const float* wts = ws + WS_WTS;
  float a = 0.f;
  #pragma unroll 4
  for (int bb = c0; bb < c1; ++bb)
    a = fmaf(part[(size_t)bb * PART_STRIDE + col], wts[bb], a);
  ws[WS_GP + g * 128 + col] = a;
}

// ---------------- K3: 2-row FFN head + logits/softmax ----------------
__global__ __launch_bounds__(256) void k_final(
    const float* __restrict__ ws,
    const float* __restrict__ Wf1, const float* __restrict__ bf1,
    const float* __restrict__ Wf2, const float* __restrict__ bf2,
    const float* __restrict__ ln2_g, const float* __restrict__ ln2_b,
    const float* __restrict__ ln3_g, const float* __restrict__ ln3_b,
    const float* __restrict__ Wl1, const float* __restrict__ bl1,
    const float* __restrict__ Wl2, const float* __restrict__ bl2,
    float* __restrict__ out)
{
  __shared__ float rowb[2][128];
  __shared__ float mmb[2][128];
  __shared__ float red[8];
  __shared__ float emb[256];
  __shared__ float abuf[64];
  __shared__ float lbuf[4];
  int tid = threadIdx.x, lane = tid & 63, wave = tid >> 6;

  if (tid < 128) {
    float v0 = ws[WS_V0 + tid];
    float a = v0 * ws[WS_E0];
    #pragma unroll
    for (int g = 0; g < NCOMB; ++g) a += ws[WS_GP + g * 128 + tid];
    rowb[0][tid] = a / ws[WS_LL];
    rowb[1][tid] = v0;
  }
  __syncthreads();

  int row = tid >> 7, k = tid & 127;
  float x = rowb[row][k];
  float ps = x, pq = x * x;
  for (int m = 1; m < 64; m <<= 1) { ps += __shfl_xor(ps, m); pq += __shfl_xor(pq, m); }
  __syncthreads();
  if (lane == 0) { red[wave] = ps; red[4 + wave] = pq; }
  __syncthreads();
  {
    float sum = red[row * 2] + red[row * 2 + 1];
    float sq  = red[4 + row * 2] + red[4 + row * 2 + 1];
    float mu = sum * (1.f / 128.f);
    float var = sq * (1.f / 128.f) - mu * mu;
    x = (x - mu) * rsqrtf(var + LN_EPS) * ln2_g[k] + ln2_b[k];
  }
  mmb[row][k] = x;
  __syncthreads();
  float t1 = bf1[k];
  for (int j = 0; j < 128; j++) t1 = fmaf(mmb[row][j], Wf1[j * 128 + k], t1);
  float gg = t1 * 0.5f * (1.f + erff(t1 * 0.70710678118654752f));
  __syncthreads();
  rowb[row][k] = gg;
  __syncthreads();
  float t2 = bf2[k];
  for (int j = 0; j < 128; j++) t2 = fmaf(rowb[row][j], Wf2[j * 128 + k], t2);
  ps = t2; pq = t2 * t2;
  for (int m = 1; m < 64; m <<= 1) { ps += __shfl_xor(ps, m); pq += __shfl_xor(pq, m); }
  __syncthreads();
  if (lane == 0) { red[wave] = ps; red[4 + wave] = pq; }
  __syncthreads();
  {
    float sum = red[row * 2] + red[row * 2 + 1];
    float sq  = red[4 + row * 2] + red[4 + row * 2 + 1];
    float mu = sum * (1.f / 128.f);
    float var = sq * (1.f / 128.f) - mu * mu;
    t2 = (t2 - mu) * rsqrtf(var + LN_EPS) * ln3_g[k] + ln3_b[k];
  }
  emb[row * 128 + k] = t2;
  __syncthreads();
  if (tid < 64) {
    float a = bl1[tid];
    for (int j = 0; j < 256; j++) a = fmaf(emb[j], Wl1[j * 64 + tid], a);
    abuf[tid] = fmaxf(a, 0.f);
  }
  __syncthreads();
  if (tid < 4) {
    float lg = bl2[tid];
    for (int j = 0; j < 64; j++) lg = fmaf(abuf[j], Wl2[j * 4 + tid], lg);
    lbuf[tid] = lg;
  }
  __syncthreads();
  if (tid < 4) {
    float m4 = fmaxf(fmaxf(lbuf[0], lbuf[1]), fmaxf(lbuf[2], lbuf[3]));
    float e0 = expf(lbuf[0] - m4), e1 = expf(lbuf[1] - m4);
    float e2 = expf(lbuf[2] - m4), e3 = expf(lbuf[3] - m4);
    float ssum = e0 + e1 + e2 + e3;
    out[tid] = lbuf[tid];
    out[4 + tid] = expf(lbuf[tid] - m4) / ssum;
  }
}

extern "C" void kernel_launch(void* const* d_in, const int* in_sizes, int n_in,
                              void* d_out, int out_size, void* d_ws, size_t ws_size,
                              hipStream_t stream) {
  const float* wsi    = (const float*)d_in[0];
  const float* x_omic = (const float*)d_in[1];
  const float* W1     = (const float*)d_in[2];
  const float* b1     = (const float*)d_in[3];
  const float* W2     = (const float*)d_in[4];
  const float* b2     = (const float*)d_in[5];
  const float* Wp     = (const float*)d_in[6];
  const float* bp     = (const float*)d_in[7];
  const float* ln1_g  = (const float*)d_in[8];
  const float* ln1_b  = (const float*)d_in[9];
  const float* Wqkv   = (const float*)d_in[10];
  const float* ln2_g  = (const float*)d_in[11];
  const float* ln2_b  = (const float*)d_in[12];
  const float* Wf1    = (const float*)d_in[13];
  const float* bf1    = (const float*)d_in[14];
  const float* Wf2    = (const float*)d_in[15];
  const float* bf2    = (const float*)d_in[16];
  const float* ln3_g  = (const float*)d_in[17];
  const float* ln3_b  = (const float*)d_in[18];
  const float* Wl1    = (const float*)d_in[19];
  const float* bl1    = (const float*)d_in[20];
  const float* Wl2    = (const float*)d_in[21];
  const float* bl2    = (const float*)d_in[22];
  float* ws   = (float*)d_ws;
  float* outp = (float*)d_out;
  ushortT* wpt  = (ushortT*)(ws + WS_WPT);
  ushortT* wkvt = (ushortT*)(ws + WS_WKVT);

  int N = in_sizes[0] / 1024;
  int d_omic = in_sizes[1];
  int NB = (N + 63) / 64;
  int chunk = (NB + NCOMB - 1) / NCOMB;

  k_prep<<<320, 256, 0, stream>>>(Wp, Wqkv, wpt, wkvt);
  k_h1<<<16, 256, 0, stream>>>(x_omic, W1, d_omic, ws);
  k_omic<<<1, 256, 0, stream>>>(b1, W2, b2, Wqkv, ln1_g, ln1_b, ws);
  k_main<<<NB, 256, 0, stream>>>(wsi, N, wpt, wkvt, bp, ln1_g, ln1_b, ws);
  k_fin0<<<1, 256, 0, stream>>>(ws, NB);
  k_fin1<<<NCOMB, 128, 0, stream>>>(ws, NB, chunk);
  k_final<<<1, 256, 0, stream>>>(ws, Wf1, bf1, Wf2, bf2, ln2_g, ln2_b,
                                 ln3_g, ln3_b, Wl1, bl1, Wl2, bl2, outp);
}

// Round 6
// 131.773 us; speedup vs baseline: 1.2320x; 1.2320x over previous
//
#include <hip/hip_runtime.h>
#include <hip/hip_bf16.h>
#include <math.h>

#define LN_EPS 1e-5f

typedef unsigned short ushortT;
typedef short bf16x8 __attribute__((ext_vector_type(8)));
typedef float f32x4 __attribute__((ext_vector_type(4)));

// ws layout (float offsets)
#define WS_QP   0            // q_p * scale (128)
#define WS_V0   128          // v0 (128)
#define WS_S0   256          // s0 scalar
#define WS_LL   258          // softmax denominator L
#define WS_E0   259          // exp(s0 - M)
#define WS_H1P  512          // 16*256 h1 partials
#define WS_PART 4608         // per-block partials: [acc 128][m][l][pad] stride 132
#define PART_STRIDE 132
#define PART_M 128
#define PART_L 129
#define WS_WTS  108000       // per-block softmax weights (NB floats)
#define WS_GP   109000       // 32 x 128 combiner partial sums
#define NCOMB   32
#define WS_WPT  131072       // ushort region: wpt2 panels [32][256m][32k] bf16 (512KB)
#define WS_WKVT 262144       // ushort region: wkvt2 panels [8][256m][32k] bf16 (128KB)

__device__ __forceinline__ float elu1(float x){ return x > 0.f ? x : expm1f(x); }
__device__ __forceinline__ unsigned pk2(float lo, float hi){
  union { __hip_bfloat162 h; unsigned u; } cv;
  cv.h = __float22bfloat162_rn(make_float2(lo, hi));
  return cv.u;
}
// async global->LDS DMA, 16B/lane, linear dest (wave-uniform base + lane*16)
__device__ __forceinline__ void dma16(const void* g, void* l) {
  __builtin_amdgcn_global_load_lds(
      (const __attribute__((address_space(1))) unsigned int*)g,
      (__attribute__((address_space(3))) unsigned int*)l, 16, 0, 0);
}
template<int N> __device__ __forceinline__ void vwait() {
  asm volatile("s_waitcnt vmcnt(%0)" :: "i"(N) : "memory");
}
__device__ __forceinline__ void lwait0() {
  asm volatile("s_waitcnt lgkmcnt(0)" ::: "memory");
}
__device__ __forceinline__ void sbar()   { __builtin_amdgcn_s_barrier(); }
__device__ __forceinline__ void schedb() { __builtin_amdgcn_sched_barrier(0); }

// ---------------- K_setup: weight panels (pre-swizzled) + h1 partial dots ----------------
// wpt2 panel kc (0..31): ushort idx = kc*8192 + m*32 + ((c ^ ((m>>1)&3))*8 + e)
//   holding Wp[kc*32 + c*8 + e][m] as bf16.  wkvt2 panel kk (0..7) same shape from
//   Wqkv[kk*32 + c*8 + e][128 + m].  Swizzle baked in -> k_main DMAs are verbatim.
__global__ __launch_bounds__(256) void k_setup(
    const float* __restrict__ Wp, const float* __restrict__ Wqkv,
    const float* __restrict__ x, const float* __restrict__ W1, int d_omic,
    ushortT* __restrict__ wpt, ushortT* __restrict__ wkvt, float* __restrict__ ws)
{
  int bb = blockIdx.x, t = threadIdx.x;
  if (bb < 32) {
    int kc = bb, m = t, sw = (m >> 1) & 3;
    #pragma unroll
    for (int c = 0; c < 4; ++c) {
      float v[8];
      #pragma unroll
      for (int e = 0; e < 8; ++e) v[e] = Wp[(size_t)(kc * 32 + c * 8 + e) * 256 + m];
      uint4 w = make_uint4(pk2(v[0], v[1]), pk2(v[2], v[3]), pk2(v[4], v[5]), pk2(v[6], v[7]));
      *(uint4*)&wpt[kc * 8192 + m * 32 + ((c ^ sw) * 8)] = w;
    }
  } else if (bb < 40) {
    int kk = bb - 32, m = t, sw = (m >> 1) & 3;
    #pragma unroll
    for (int c = 0; c < 4; ++c) {
      float v[8];
      #pragma unroll
      for (int e = 0; e < 8; ++e) v[e] = Wqkv[(size_t)(kk * 32 + c * 8 + e) * 384 + 128 + m];
      uint4 w = make_uint4(pk2(v[0], v[1]), pk2(v[2], v[3]), pk2(v[4], v[5]), pk2(v[6], v[7]));
      *(uint4*)&wkvt[kk * 8192 + m * 32 + ((c ^ sw) * 8)] = w;
    }
  } else {
    int g = bb - 40;
    int i0 = g * 99, i1 = min(i0 + 99, d_omic);
    __shared__ float xs[112];
    for (int i = i0 + t; i < i1; i += 256) xs[i - i0] = x[i];
    __syncthreads();
    float s = 0.f;
    for (int i = i0; i < i1; i++) s = fmaf(xs[i - i0], W1[(size_t)i * 256 + t], s);
    ws[WS_H1P + g * 256 + t] = s;
  }
}

// ---------------- K1: omic MLP + token0 LN1 + q_p/k_p/v0 + s0 (exact fp32) ----------------
__global__ __launch_bounds__(256) void k_omic(
    const float* __restrict__ b1,
    const float* __restrict__ W2, const float* __restrict__ b2,
    const float* __restrict__ Wqkv,
    const float* __restrict__ ln1_g, const float* __restrict__ ln1_b,
    float* __restrict__ ws)
{
  __shared__ float h1[256];
  __shared__ float xn0[256];
  __shared__ float qs[128], ks[128];
  __shared__ float red[8];
  int tid = threadIdx.x, lane = tid & 63, wave = tid >> 6;

  float s = b1[tid];
  for (int g = 0; g < 16; g++) s += ws[WS_H1P + g * 256 + tid];
  h1[tid] = elu1(s);
  __syncthreads();

  s = b2[tid];
  for (int i = 0; i < 256; i++) s = fmaf(h1[i], W2[i * 256 + tid], s);
  float t0 = elu1(s);

  float ps = t0, pq = t0 * t0;
  for (int m = 1; m < 64; m <<= 1) { ps += __shfl_xor(ps, m); pq += __shfl_xor(pq, m); }
  if (lane == 0) { red[wave] = ps; red[4 + wave] = pq; }
  __syncthreads();
  float mu = (red[0] + red[1] + red[2] + red[3]) * (1.f / 256.f);
  float var = (red[4] + red[5] + red[6] + red[7]) * (1.f / 256.f) - mu * mu;
  float xn = (t0 - mu) * rsqrtf(var + LN_EPS) * ln1_g[tid] + ln1_b[tid];
  xn0[tid] = xn;
  __syncthreads();

  float a = 0.f;
  for (int j = 0; j < 256; j++) a = fmaf(xn0[j], Wqkv[j * 384 + tid], a);
  if (tid < 128) { float q = a * 0.088388347648318447f; qs[tid] = q; ws[WS_QP + tid] = q; }
  else           { ks[tid - 128] = a; }
  if (tid < 128) {
    float av = 0.f;
    for (int j = 0; j < 256; j++) av = fmaf(xn0[j], Wqkv[j * 384 + 256 + tid], av);
    ws[WS_V0 + tid] = av;
  }
  __syncthreads();
  float p = (tid < 128) ? qs[tid] * ks[tid] : 0.f;
  for (int m = 1; m < 64; m <<= 1) p += __shfl_xor(p, m);
  if (lane == 0) red[wave] = p;
  __syncthreads();
  if (tid == 0) ws[WS_S0] = red[0] + red[1] + red[2] + red[3];
}

// ---------------- K2: BM=128, 8-wave MFMA fused kernel ----------------
// Wave grid: cg = wv&3 (64 out-cols), rg = wv>>2 (64 rows).
// Phase 1: T = wsi[128r] @ Wp (K=1024, 32 slices of K32, 2-slot dbuf, vwait<4>).
// Phase 2: [k|v] = xn @ Wkv (K=256, barrier-free: wkv frags from L2, Xn from LDS).
__global__ __launch_bounds__(512, 4) void k_main(
    const float* __restrict__ wsi, int N,
    const ushortT* __restrict__ wpt, const ushortT* __restrict__ wkvt,
    const float* __restrict__ bp,
    const float* __restrict__ ln1_g, const float* __restrict__ ln1_b,
    float* __restrict__ ws)
{
  // U: [0..32K) 2x wsi slice (16KB each) ; Uw=[32K..64K) 2x wpt slice.
  // After phase 1: U[0..4K)=LN red, then U[0..64K)=Xn[128][256] bf16 swizzled.
  // After phase 2: U[0..1K)=sred, [1K..1056)=aux, [1056..1568)=wts, [1600..2624)=vred.
  __shared__ __align__(16) char U[65536];
  char* Uw = U + 32768;

  const int tid = threadIdx.x;
  const int lane = tid & 63, wv = tid >> 6;
  const int l15 = lane & 15, lh = lane >> 4;
  const int cg = wv & 3, rg = wv >> 2;
  const int b = blockIdx.x, r0 = b * 128;

  // ---- DMA source indices ----
  int wsiSrc[2];
  #pragma unroll
  for (int i = 0; i < 2; ++i) {
    int rowL = 16 * wv + 8 * i + (lane >> 3);
    int gr = r0 + rowL; gr = (gr < N) ? gr : (N - 1);
    wsiSrc[i] = gr * 1024 + (((lane & 7) ^ (lane >> 3)) << 2);
  }
  int wptSrc[2];
  #pragma unroll
  for (int j = 0; j < 2; ++j) wptSrc[j] = (32 * wv + 16 * j) * 32 + lane * 8;

  // read-side constants
  const unsigned afslot = (unsigned)((lh ^ ((l15 >> 1) & 3)) << 4);  // wpt frag slot
  const unsigned bs0 = (unsigned)(((2 * lh)     ^ (l15 & 7)) << 4);  // wsi chunk slots
  const unsigned bs1 = (unsigned)(((2 * lh + 1) ^ (l15 & 7)) << 4);

  const f32x4 z4 = {0.f, 0.f, 0.f, 0.f};
  f32x4 acc[4][4];
  #pragma unroll
  for (int mt = 0; mt < 4; ++mt)
    #pragma unroll
    for (int nt = 0; nt < 4; ++nt) acc[mt][nt] = z4;

  auto dmaSlice = [&](int kc, int k) {
    char* ds = U + k * 16384 + wv * 2048;
    #pragma unroll
    for (int i = 0; i < 2; ++i) dma16(wsi + wsiSrc[i] + kc * 32, ds + i * 1024);
    char* dw = Uw + k * 16384 + wv * 2048;
    #pragma unroll
    for (int j = 0; j < 2; ++j) dma16(wpt + wptSrc[j] + kc * 8192, dw + j * 1024);
  };

  // ---- phase 1 ----
  dmaSlice(0, 0);
  for (int s = 0; s < 32; ++s) {
    if (s < 31) { dmaSlice(s + 1, (s + 1) & 1); vwait<4>(); }
    else vwait<0>();
    sbar(); schedb();
    {
      const char* Ws = U  + (s & 1) * 16384;
      const char* Wf = Uw + (s & 1) * 16384;
      bf16x8 af[4], bfr[4];
      #pragma unroll
      for (int mt = 0; mt < 4; ++mt)
        af[mt] = *(const bf16x8*)(Wf + (64 * cg + 16 * mt + l15) * 64 + afslot);
      #pragma unroll
      for (int nt = 0; nt < 4; ++nt) {
        const char* p = Ws + (64 * rg + 16 * nt + l15) * 128;
        uint4 ua = *(const uint4*)(p + bs0);
        uint4 ub = *(const uint4*)(p + bs1);
        union { unsigned u[4]; bf16x8 v; } cv;
        cv.u[0] = pk2(__uint_as_float(ua.x), __uint_as_float(ua.y));
        cv.u[1] = pk2(__uint_as_float(ua.z), __uint_as_float(ua.w));
        cv.u[2] = pk2(__uint_as_float(ub.x), __uint_as_float(ub.y));
        cv.u[3] = pk2(__uint_as_float(ub.z), __uint_as_float(ub.w));
        bfr[nt] = cv.v;
      }
      #pragma unroll
      for (int mt = 0; mt < 4; ++mt)
        #pragma unroll
        for (int nt = 0; nt < 4; ++nt)
          acc[mt][nt] = __builtin_amdgcn_mfma_f32_16x16x32_bf16(af[mt], bfr[nt], acc[mt][nt], 0, 0, 0);
    }
    sbar(); schedb();
  }

  // ---- bias + LN1 (cross-cg reduction via red[row][cg][2] at U[0..4K)) ----
  float* red = (float*)U;
  float4 bp4[4], g4[4], b4[4];
  #pragma unroll
  for (int mt = 0; mt < 4; ++mt) {
    int m0 = 64 * cg + 16 * mt + 4 * lh;
    bp4[mt] = *(const float4*)&bp[m0];
    g4[mt]  = *(const float4*)&ln1_g[m0];
    b4[mt]  = *(const float4*)&ln1_b[m0];
  }
  float ps[4], pq[4];
  #pragma unroll
  for (int nt = 0; nt < 4; ++nt) { ps[nt] = 0.f; pq[nt] = 0.f; }
  #pragma unroll
  for (int mt = 0; mt < 4; ++mt) {
    const float bb4[4] = {bp4[mt].x, bp4[mt].y, bp4[mt].z, bp4[mt].w};
    #pragma unroll
    for (int nt = 0; nt < 4; ++nt)
      #pragma unroll
      for (int r = 0; r < 4; ++r) {
        float v = acc[mt][nt][r] + bb4[r];
        acc[mt][nt][r] = v;
        ps[nt] += v; pq[nt] += v * v;
      }
  }
  #pragma unroll
  for (int nt = 0; nt < 4; ++nt) {
    ps[nt] += __shfl_xor(ps[nt], 16); pq[nt] += __shfl_xor(pq[nt], 16);
    ps[nt] += __shfl_xor(ps[nt], 32); pq[nt] += __shfl_xor(pq[nt], 32);
  }
  if (lh == 0) {
    #pragma unroll
    for (int nt = 0; nt < 4; ++nt) {
      int row = 64 * rg + 16 * nt + l15;
      *(float2*)&red[row * 8 + cg * 2] = make_float2(ps[nt], pq[nt]);
    }
  }
  lwait0(); sbar(); schedb();
  float mu[4], rstd[4];
  #pragma unroll
  for (int nt = 0; nt < 4; ++nt) {
    int row = 64 * rg + 16 * nt + l15;
    float s_ = 0.f, q_ = 0.f;
    #pragma unroll
    for (int c = 0; c < 4; ++c) { s_ += red[row * 8 + c * 2]; q_ += red[row * 8 + c * 2 + 1]; }
    float m_ = s_ * (1.f / 256.f);
    float v_ = q_ * (1.f / 256.f) - m_ * m_;
    mu[nt] = m_; rstd[nt] = rsqrtf(v_ + LN_EPS);
  }
  lwait0(); sbar(); schedb();     // all red reads done before Xn overwrites U

  // ---- write Xn[128][256] bf16 (swizzled) over U ----
  #pragma unroll
  for (int nt = 0; nt < 4; ++nt) {
    int row = 64 * rg + 16 * nt + l15;
    unsigned rswz = (unsigned)((row & 7) << 4);
    #pragma unroll
    for (int mt = 0; mt < 4; ++mt) {
      float x0 = (acc[mt][nt][0] - mu[nt]) * rstd[nt] * g4[mt].x + b4[mt].x;
      float x1 = (acc[mt][nt][1] - mu[nt]) * rstd[nt] * g4[mt].y + b4[mt].y;
      float x2 = (acc[mt][nt][2] - mu[nt]) * rstd[nt] * g4[mt].z + b4[mt].z;
      float x3 = (acc[mt][nt][3] - mu[nt]) * rstd[nt] * g4[mt].w + b4[mt].w;
      unsigned off = (unsigned)(row * 512 + (64 * cg + 16 * mt + 4 * lh) * 2) ^ rswz;
      *(uint2*)(U + off) = make_uint2(pk2(x0, x1), pk2(x2, x3));
    }
  }
  lwait0(); sbar(); schedb();

  // ---- phase 2 (barrier-free): D2[m=kvcol][n=row], K=256 ----
  f32x4 acc2[4][4];
  #pragma unroll
  for (int mt = 0; mt < 4; ++mt)
    #pragma unroll
    for (int nt = 0; nt < 4; ++nt) acc2[mt][nt] = z4;
  int kvBase[4];
  #pragma unroll
  for (int mt = 0; mt < 4; ++mt) {
    int m = 64 * cg + 16 * mt + l15;
    kvBase[mt] = m * 32 + ((lh ^ ((m >> 1) & 3)) << 3);
  }
  // 2-deep register prefetch of wkv fragments from L2
  bf16x8 gA[4], gB[4];
  #pragma unroll
  for (int mt = 0; mt < 4; ++mt) gA[mt] = *(const bf16x8*)(wkvt + kvBase[mt]);
  #pragma unroll
  for (int kp = 0; kp < 4; ++kp) {
    const int kk0 = 2 * kp, kk1 = 2 * kp + 1;
    #pragma unroll
    for (int mt = 0; mt < 4; ++mt)
      gB[mt] = *(const bf16x8*)(wkvt + kvBase[mt] + kk1 * 8192);
    {
      bf16x8 bfr[4];
      #pragma unroll
      for (int nt = 0; nt < 4; ++nt) {
        int row = 64 * rg + 16 * nt + l15;
        unsigned off = (unsigned)(row * 512 + kk0 * 64 + lh * 16) ^ (unsigned)((row & 7) << 4);
        bfr[nt] = *(const bf16x8*)(U + off);
      }
      #pragma unroll
      for (int mt = 0; mt < 4; ++mt)
        #pragma unroll
        for (int nt = 0; nt < 4; ++nt)
          acc2[mt][nt] = __builtin_amdgcn_mfma_f32_16x16x32_bf16(gA[mt], bfr[nt], acc2[mt][nt], 0, 0, 0);
    }
    if (kp < 3) {
      #pragma unroll
      for (int mt = 0; mt < 4; ++mt)
        gA[mt] = *(const bf16x8*)(wkvt + kvBase[mt] + (kk0 + 2) * 8192);
    }
    {
      bf16x8 bfr[4];
      #pragma unroll
      for (int nt = 0; nt < 4; ++nt) {
        int row = 64 * rg + 16 * nt + l15;
        unsigned off = (unsigned)(row * 512 + kk1 * 64 + lh * 16) ^ (unsigned)((row & 7) << 4);
        bfr[nt] = *(const bf16x8*)(U + off);
      }
      #pragma unroll
      for (int mt = 0; mt < 4; ++mt)
        #pragma unroll
        for (int nt = 0; nt < 4; ++nt)
          acc2[mt][nt] = __builtin_amdgcn_mfma_f32_16x16x32_bf16(gB[mt], bfr[nt], acc2[mt][nt], 0, 0, 0);
    }
  }
  sbar(); schedb();               // all Xn reads done; U reusable

  float* sred = (float*)U;                 // [2cg][128row]
  float* aux  = (float*)(U + 1024);        // [4]
  float* wts  = (float*)(U + 1056);        // [128]
  float* vred = (float*)(U + 1600);        // [2rg][128col]
  float* part = ws + WS_PART + (size_t)b * PART_STRIDE;

  // ---- scores (cg 0,1 hold k-proj cols) ----
  if (cg < 2) {
    float4 qp4[4];
    #pragma unroll
    for (int mt = 0; mt < 4; ++mt)
      qp4[mt] = *(const float4*)&ws[WS_QP + 64 * cg + 16 * mt + 4 * lh];
    float sp[4];
    #pragma unroll
    for (int nt = 0; nt < 4; ++nt) {
      float s_ = 0.f;
      #pragma unroll
      for (int mt = 0; mt < 4; ++mt) {
        s_ = fmaf(qp4[mt].x, acc2[mt][nt][0], s_);
        s_ = fmaf(qp4[mt].y, acc2[mt][nt][1], s_);
        s_ = fmaf(qp4[mt].z, acc2[mt][nt][2], s_);
        s_ = fmaf(qp4[mt].w, acc2[mt][nt][3], s_);
      }
      sp[nt] = s_;
    }
    #pragma unroll
    for (int nt = 0; nt < 4; ++nt) {
      sp[nt] += __shfl_xor(sp[nt], 16);
      sp[nt] += __shfl_xor(sp[nt], 32);
    }
    if (lh == 0) {
      #pragma unroll
      for (int nt = 0; nt < 4; ++nt) sred[cg * 128 + 64 * rg + 16 * nt + l15] = sp[nt];
    }
  }
  lwait0(); sbar(); schedb();

  // ---- softmax over 128 rows (waves 0,1) ----
  float sv = -INFINITY, ev = 0.f;
  if (tid < 128) {
    sv = sred[tid] + sred[128 + tid];
    if (r0 + tid >= N) sv = -INFINITY;
  }
  float mb = sv;
  #pragma unroll
  for (int m = 1; m < 64; m <<= 1) mb = fmaxf(mb, __shfl_xor(mb, m));
  if (tid < 128 && lane == 0) aux[tid >> 6] = mb;
  lwait0(); sbar(); schedb();
  float M2 = fmaxf(aux[0], aux[1]);
  if (tid < 128) { ev = (r0 + tid < N) ? expf(sv - M2) : 0.f; wts[tid] = ev; }
  float lsum = ev;
  #pragma unroll
  for (int m = 1; m < 64; m <<= 1) lsum += __shfl_xor(lsum, m);
  if (tid < 128 && lane == 0) aux[2 + (tid >> 6)] = lsum;
  lwait0(); sbar(); schedb();
  if (tid == 0) { part[PART_M] = M2; part[PART_L] = aux[2] + aux[3]; }

  // ---- weighted-V partials (cg 2,3 hold v-proj cols) ----
  if (cg >= 2) {
    float wr[4];
    #pragma unroll
    for (int nt = 0; nt < 4; ++nt) wr[nt] = wts[64 * rg + 16 * nt + l15];
    #pragma unroll
    for (int mt = 0; mt < 4; ++mt) {
      float vs0 = 0.f, vs1 = 0.f, vs2 = 0.f, vs3 = 0.f;
      #pragma unroll
      for (int nt = 0; nt < 4; ++nt) {
        vs0 = fmaf(wr[nt], acc2[mt][nt][0], vs0);
        vs1 = fmaf(wr[nt], acc2[mt][nt][1], vs1);
        vs2 = fmaf(wr[nt], acc2[mt][nt][2], vs2);
        vs3 = fmaf(wr[nt], acc2[mt][nt][3], vs3);
      }
      #pragma unroll
      for (int m = 1; m < 16; m <<= 1) {
        vs0 += __shfl_xor(vs0, m); vs1 += __shfl_xor(vs1, m);
        vs2 += __shfl_xor(vs2, m); vs3 += __shfl_xor(vs3, m);
      }
      if (l15 == 0)
        *(float4*)&vred[128 * rg + 64 * (cg - 2) + 16 * mt + 4 * lh] =
            make_float4(vs0, vs1, vs2, vs3);
    }
  }
  lwait0(); sbar(); schedb();
  if (tid < 128) part[tid] = vred[tid] + vred[128 + tid];
}

// ---------------- K_fin0: global max M, per-block weights, denominator L ----------------
__global__ __launch_bounds__(256) void k_fin0(float* __restrict__ ws, int NB)
{
  __shared__ float red[8];
  int tid = threadIdx.x, lane = tid & 63, wave = tid >> 6;
  const float* part = ws + WS_PART;
  float s0 = ws[WS_S0];

  float mloc = s0;
  for (int bb = tid; bb < NB; bb += 256) mloc = fmaxf(mloc, part[(size_t)bb * PART_STRIDE + PART_M]);
  for (int m = 1; m < 64; m <<= 1) mloc = fmaxf(mloc, __shfl_xor(mloc, m));
  if (lane == 0) red[wave] = mloc;
  __syncthreads();
  float M = fmaxf(fmaxf(red[0], red[1]), fmaxf(red[2], red[3]));

  float lp = 0.f;
  for (int bb = tid; bb < NB; bb += 256) {
    float w = expf(part[(size_t)bb * PART_STRIDE + PART_M] - M);
    ws[WS_WTS + bb] = w;
    lp = fmaf(part[(size_t)bb * PART_STRIDE + PART_L], w, lp);
  }
  for (int m = 1; m < 64; m <<= 1) lp += __shfl_xor(lp, m);
  __syncthreads();
  if (lane == 0) red[wave] = lp;
  __syncthreads();
  if (tid == 0) {
    float e0 = expf(s0 - M);
    ws[WS_LL] = red[0] + red[1] + red[2] + red[3] + e0;
    ws[WS_E0] = e0;
  }
}

// ---------------- K_fin1: 32-way parallel weighted partial combine ----------------
__global__ __launch_bounds__(128) void k_fin1(float* __restrict__ ws, int NB, int chunk)
{
  int g = blockIdx.x, col = threadIdx.x;
  int c0 = g * chunk, c1 = min(c0 + chunk, NB);
  const float* part = ws + WS_PART;
  const float* wts = ws + WS_WTS;
  float a = 0.f;
  #pragma unroll 4
  for (int bb = c0; bb < c1; ++bb)
    a = fmaf(part[(size_t)bb * PART_STRIDE + col], wts[bb], a);
  ws[WS_GP + g * 128 + col] = a;
}

// ---------------- K3: 2-row FFN head + logits/softmax ----------------
__global__ __launch_bounds__(256) void k_final(
    const float* __restrict__ ws,
    const float* __restrict__ Wf1, const float* __restrict__ bf1,
    const float* __restrict__ Wf2, const float* __restrict__ bf2,
    const float* __restrict__ ln2_g, const float* __restrict__ ln2_b,
    const float* __restrict__ ln3_g, const float* __restrict__ ln3_b,
    const float* __restrict__ Wl1, const float* __restrict__ bl1,
    const float* __restrict__ Wl2, const float* __restrict__ bl2,
    float* __restrict__ out)
{
  __shared__ float rowb[2][128];
  __shared__ float mmb[2][128];
  __shared__ float red[8];
  __shared__ float emb[256];
  __shared__ float abuf[64];
  __shared__ float lbuf[4];
  int tid = threadIdx.x, lane = tid & 63, wave = tid >> 6;

  if (tid < 128) {
    float v0 = ws[WS_V0 + tid];
    float a = v0 * ws[WS_E0];
    #pragma unroll
    for (int g = 0; g < NCOMB; ++g) a += ws[WS_GP + g * 128 + tid];
    rowb[0][tid] = a / ws[WS_LL];
    rowb[1][tid] = v0;
  }
  __syncthreads();

  int row = tid >> 7, k = tid & 127;
  float x = rowb[row][k];
  float ps = x, pq = x * x;
  for (int m = 1; m < 64; m <<= 1) { ps += __shfl_xor(ps, m); pq += __shfl_xor(pq, m); }
  __syncthreads();
  if (lane == 0) { red[wave] = ps; red[4 + wave] = pq; }
  __syncthreads();
  {
    float sum = red[row * 2] + red[row * 2 + 1];
    float sq  = red[4 + row * 2] + red[4 + row * 2 + 1];
    float mu = sum * (1.f / 128.f);
    float var = sq * (1.f / 128.f) - mu * mu;
    x = (x - mu) * rsqrtf(var + LN_EPS) * ln2_g[k] + ln2_b[k];
  }
  mmb[row][k] = x;
  __syncthreads();
  float t1 = bf1[k];
  for (int j = 0; j < 128; j++) t1 = fmaf(mmb[row][j], Wf1[j * 128 + k], t1);
  float gg = t1 * 0.5f * (1.f + erff(t1 * 0.70710678118654752f));
  __syncthreads();
  rowb[row][k] = gg;
  __syncthreads();
  float t2 = bf2[k];
  for (int j = 0; j < 128; j++) t2 = fmaf(rowb[row][j], Wf2[j * 128 + k], t2);
  ps = t2; pq = t2 * t2;
  for (int m = 1; m < 64; m <<= 1) { ps += __shfl_xor(ps, m); pq += __shfl_xor(pq, m); }
  __syncthreads();
  if (lane == 0) { red[wave] = ps; red[4 + wave] = pq; }
  __syncthreads();
  {
    float sum = red[row * 2] + red[row * 2 + 1];
    float sq  = red[4 + row * 2] + red[4 + row * 2 + 1];
    float mu = sum * (1.f / 128.f);
    float var = sq * (1.f / 128.f) - mu * mu;
    t2 = (t2 - mu) * rsqrtf(var + LN_EPS) * ln3_g[k] + ln3_b[k];
  }
  emb[row * 128 + k] = t2;
  __syncthreads();
  if (tid < 64) {
    float a = bl1[tid];
    for (int j = 0; j < 256; j++) a = fmaf(emb[j], Wl1[j * 64 + tid], a);
    abuf[tid] = fmaxf(a, 0.f);
  }
  __syncthreads();
  if (tid < 4) {
    float lg = bl2[tid];
    for (int j = 0; j < 64; j++) lg = fmaf(abuf[j], Wl2[j * 4 + tid], lg);
    lbuf[tid] = lg;
  }
  __syncthreads();
  if (tid < 4) {
    float m4 = fmaxf(fmaxf(lbuf[0], lbuf[1]), fmaxf(lbuf[2], lbuf[3]));
    float e0 = expf(lbuf[0] - m4), e1 = expf(lbuf[1] - m4);
    float e2 = expf(lbuf[2] - m4), e3 = expf(lbuf[3] - m4);
    float ssum = e0 + e1 + e2 + e3;
    out[tid] = lbuf[tid];
    out[4 + tid] = expf(lbuf[tid] - m4) / ssum;
  }
}

extern "C" void kernel_launch(void* const* d_in, const int* in_sizes, int n_in,
                              void* d_out, int out_size, void* d_ws, size_t ws_size,
                              hipStream_t stream) {
  const float* wsi    = (const float*)d_in[0];
  const float* x_omic = (const float*)d_in[1];
  const float* W1     = (const float*)d_in[2];
  const float* b1     = (const float*)d_in[3];
  const float* W2     = (const float*)d_in[4];
  const float* b2     = (const float*)d_in[5];
  const float* Wp     = (const float*)d_in[6];
  const float* bp     = (const float*)d_in[7];
  const float* ln1_g  = (const float*)d_in[8];
  const float* ln1_b  = (const float*)d_in[9];
  const float* Wqkv   = (const float*)d_in[10];
  const float* ln2_g  = (const float*)d_in[11];
  const float* ln2_b  = (const float*)d_in[12];
  const float* Wf1    = (const float*)d_in[13];
  const float* bf1    = (const float*)d_in[14];
  const float* Wf2    = (const float*)d_in[15];
  const float* bf2    = (const float*)d_in[16];
  const float* ln3_g  = (const float*)d_in[17];
  const float* ln3_b  = (const float*)d_in[18];
  const float* Wl1    = (const float*)d_in[19];
  const float* bl1    = (const float*)d_in[20];
  const float* Wl2    = (const float*)d_in[21];
  const float* bl2    = (const float*)d_in[22];
  float* ws   = (float*)d_ws;
  float* outp = (float*)d_out;
  ushortT* wpt  = (ushortT*)(ws + WS_WPT);
  ushortT* wkvt = (ushortT*)(ws + WS_WKVT);

  int N = in_sizes[0] / 1024;
  int d_omic = in_sizes[1];
  int NB = (N + 127) / 128;
  int chunk = (NB + NCOMB - 1) / NCOMB;

  k_setup<<<56, 256, 0, stream>>>(Wp, Wqkv, x_omic, W1, d_omic, wpt, wkvt, ws);
  k_omic<<<1, 256, 0, stream>>>(b1, W2, b2, Wqkv, ln1_g, ln1_b, ws);
  k_main<<<NB, 512, 0, stream>>>(wsi, N, wpt, wkvt, bp, ln1_g, ln1_b, ws);
  k_fin0<<<1, 256, 0, stream>>>(ws, NB);
  k_fin1<<<NCOMB, 128, 0, stream>>>(ws, NB, chunk);
  k_final<<<1, 256, 0, stream>>>(ws, Wf1, bf1, Wf2, bf2, ln2_g, ln2_b,
                                 ln3_g, ln3_b, Wl1, bl1, Wl2, bl2, outp);
}